// Round 3
// baseline (632.533 us; speedup 1.0000x reference)
//
#include <hip/hip_runtime.h>

// Problem constants
static constexpr int Nn_ = 32, Cc_ = 64, Hh_ = 64, Ww_ = 64;
static constexpr int K_ = 512;
static constexpr int HW_ = Hh_ * Ww_;             // 4096
static constexpr int CHW_ = Cc_ * HW_;            // 262144
static constexpr int T_ = Nn_ * Hh_ * Ww_;        // 131072 tokens
static constexpr int OUT_ELEMS = Nn_ * Cc_ * Hh_ * Ww_;  // 8388608
// d_out layout: [out][codebook_new (32768)][N_new (512)][m_new (32768)]
static constexpr int OFF_CB = OUT_ELEMS;
static constexpr int OFF_N  = OUT_ELEMS + 32768;
static constexpr int OFF_M  = OUT_ELEMS + 32768 + 512;

static constexpr int S_ = 32;   // stats slices == images

// ws layout (floats):
// [0, 131072)   idx per token (int)
// [T_, T_+512)  cnorm2
// [WS_PSUM, +S_*512*64)  per-slice partial sums [s][c][k]
// [WS_PCNT, +S_*512)     per-slice partial counts [s][k]
static constexpr int WS_IDX   = 0;
static constexpr int WS_CNORM = T_;
static constexpr int WS_PSUM  = T_ + 512;
static constexpr int WS_PCNT  = WS_PSUM + S_ * K_ * Cc_;
// total = 131072+512+1048576+16384 floats ~= 4.8 MB

// K0: |c|^2 per codeword
__global__ __launch_bounds__(256) void k_prep(const float* __restrict__ cb,
                                              float* __restrict__ ws) {
    int i = blockIdx.x * 256 + threadIdx.x;
    if (i < K_) {
        const float* r = cb + i * 64;
        float a = 0.f;
#pragma unroll
        for (int j = 0; j < 64; ++j) a = fmaf(r[j], r[j], a);
        ws[WS_CNORM + i] = a;
    }
}

// K1: one block (4 waves) per (n,h) row of 64 tokens; wave wi scans 128 codewords.
__global__ __launch_bounds__(256) void k_assign(const float* __restrict__ x,
                                                const float* __restrict__ cb,
                                                float* __restrict__ ws,
                                                float* __restrict__ out) {
    const float* cnorm2 = ws + WS_CNORM;
    int* idx_out = (int*)(ws + WS_IDX);

    __shared__ float red_d[4][64];
    __shared__ int   red_i[4][64];

    const int row  = blockIdx.x;          // n*64 + h
    const int lane = threadIdx.x & 63;    // w
    const int wi   = threadIdx.x >> 6;    // wave 0..3
    const int n = row >> 6, h = row & 63;
    const int base = n * CHW_ + h * Ww_ + lane;

    // full channel vector for this token (coalesced per channel)
    float xr[64];
#pragma unroll
    for (int c = 0; c < 64; ++c) xr[c] = x[base + c * HW_];

    float xn = 0.f;
#pragma unroll
    for (int c = 0; c < 64; ++c) xn = fmaf(xr[c], xr[c], xn);

    float best = __builtin_inff();
    int bidx = wi * 128;
    const int k0 = wi * 128;
    for (int k = k0; k < k0 + 128; ++k) {
        const float* __restrict__ cr = cb + k * 64;   // wave-uniform -> s_load
        float acc = 0.f;
#pragma unroll
        for (int j = 0; j < 64; ++j) acc = fmaf(xr[j], cr[j], acc);
        float d2 = (xn - 2.0f * acc) + cnorm2[k];
        if (d2 < best) { best = d2; bidx = k; }       // strict < == first-min
    }

    red_d[wi][lane] = best;
    red_i[wi][lane] = bidx;
    __syncthreads();
    if (wi == 0) {
        float b = red_d[0][lane];
        int  bi = red_i[0][lane];
#pragma unroll
        for (int p = 1; p < 4; ++p) {
            float d = red_d[p][lane];
            if (d < b) { b = d; bi = red_i[p][lane]; }  // ascending range, strict <
        }
        red_i[0][lane] = bi;
        idx_out[row * 64 + lane] = bi;                  // coalesced
    }
    __syncthreads();
    const int fb = red_i[0][lane];
    const float* __restrict__ q = cb + fb * 64;         // L1/L2-hot gather
#pragma unroll
    for (int cc = 0; cc < 16; ++cc) {
        int c = wi * 16 + cc;
        out[base + c * HW_] = q[c];                     // coalesced store per channel
    }
}

// K2: block = (channel c, image s). Coalesced x/idx reads, LDS histogram scatter.
__global__ __launch_bounds__(256) void k_stats(const float* __restrict__ x,
                                               const float* __restrict__ ws_ro,
                                               float* __restrict__ ws) {
    const int* __restrict__ idx = (const int*)(ws_ro + WS_IDX);
    __shared__ float hist[512];
    __shared__ float hcnt[512];

    const int c = blockIdx.x & 63;
    const int s = blockIdx.x >> 6;
    const int tid = threadIdx.x;
    const bool docnt = (c == 0);

    hist[tid] = 0.f; hist[tid + 256] = 0.f;
    hcnt[tid] = 0.f; hcnt[tid + 256] = 0.f;
    __syncthreads();

    const float* __restrict__ xc = x + s * CHW_ + c * HW_;  // contiguous 16 KB
    const int tbase = s * HW_;
#pragma unroll 4
    for (int it = 0; it < 16; ++it) {
        int i = it * 256 + tid;
        int ii = idx[tbase + i];       // coalesced, L2-hot
        float xv = xc[i];              // coalesced
        atomicAdd(&hist[ii], xv);      // LDS scatter, ~2-way banks
        if (docnt) atomicAdd(&hcnt[ii], 1.0f);
    }
    __syncthreads();

    float* psum = ws + WS_PSUM + s * (K_ * Cc_) + c * K_;
    psum[tid] = hist[tid];
    psum[tid + 256] = hist[tid + 256];
    if (docnt) {
        float* pc = ws + WS_PCNT + s * K_;
        pc[tid] = hcnt[tid];
        pc[tid + 256] = hcnt[tid + 256];
    }
}

// K3: reduce slices, finalize EMA states and codebook_new
__global__ __launch_bounds__(256) void k_final(const float* __restrict__ Ns,
                                               const float* __restrict__ ms,
                                               const float* __restrict__ ws,
                                               float* __restrict__ out) {
    int j = blockIdx.x * 256 + threadIdx.x;  // j = c*512 + k  (coalesced partial reads)
    int c = j >> 9, k = j & 511;

    float s = 0.f, cnt = 0.f;
    for (int sl = 0; sl < S_; ++sl) {
        s   += ws[WS_PSUM + sl * (K_ * Cc_) + j];
        cnt += ws[WS_PCNT + sl * K_ + k];
    }

    const float gamma = 0.99f;
    const float omg   = (float)(1.0 - 0.99);

    bool occ = cnt > 0.0f;
    float Nv = Ns[k];
    float Nnew = occ ? (Nv * gamma + cnt * omg) : Nv;

    int i = k * 64 + c;
    float mv = ms[i];
    float mnew = occ ? (mv * gamma + s * omg) : mv;

    out[OFF_CB + i] = mnew / Nnew;
    out[OFF_M  + i] = mnew;
    if (c == 0) out[OFF_N + k] = Nnew;
}

extern "C" void kernel_launch(void* const* d_in, const int* in_sizes, int n_in,
                              void* d_out, int out_size, void* d_ws, size_t ws_size,
                              hipStream_t stream) {
    const float* x  = (const float*)d_in[0];
    const float* cb = (const float*)d_in[1];
    const float* Ns = (const float*)d_in[2];
    const float* ms = (const float*)d_in[3];
    float* out = (float*)d_out;
    float* ws  = (float*)d_ws;

    hipLaunchKernelGGL(k_prep,   dim3(2),           dim3(256), 0, stream, cb, ws);
    hipLaunchKernelGGL(k_assign, dim3(Nn_ * Hh_),   dim3(256), 0, stream, x, cb, ws, out);
    hipLaunchKernelGGL(k_stats,  dim3(S_ * Cc_),    dim3(256), 0, stream, x, ws, ws);
    hipLaunchKernelGGL(k_final,  dim3(32768 / 256), dim3(256), 0, stream, Ns, ms, ws, out);
}

// Round 4
// 300.393 us; speedup vs baseline: 2.1057x; 2.1057x over previous
//
#include <hip/hip_runtime.h>

// Problem constants
static constexpr int Nn_ = 32, Cc_ = 64, Hh_ = 64, Ww_ = 64;
static constexpr int K_ = 512;
static constexpr int HW_ = Hh_ * Ww_;             // 4096
static constexpr int CHW_ = Cc_ * HW_;            // 262144
static constexpr int T_ = Nn_ * Hh_ * Ww_;        // 131072 tokens
static constexpr int OUT_ELEMS = Nn_ * Cc_ * Hh_ * Ww_;  // 8388608
// d_out layout: [out][codebook_new (32768)][N_new (512)][m_new (32768)]
static constexpr int OFF_CB = OUT_ELEMS;
static constexpr int OFF_N  = OUT_ELEMS + 32768;
static constexpr int OFF_M  = OUT_ELEMS + 32768 + 512;

static constexpr int S_ = 32;   // stats slices == images

// ws layout (floats):
// [0, 131072)   idx per token (int)
// [T_, T_+512)  cnorm2
// [WS_PSUM, +S_*512*64)  per-slice partial sums [s][c][k]
// [WS_PCNT, +S_*512)     per-slice partial counts [s][k]
static constexpr int WS_IDX   = 0;
static constexpr int WS_CNORM = T_;
static constexpr int WS_PSUM  = T_ + 512;
static constexpr int WS_PCNT  = WS_PSUM + S_ * K_ * Cc_;

// K0: |c|^2 per codeword
__global__ __launch_bounds__(256) void k_prep(const float* __restrict__ cb,
                                              float* __restrict__ ws) {
    int i = blockIdx.x * 256 + threadIdx.x;
    if (i < K_) {
        const float* r = cb + i * 64;
        float a = 0.f;
#pragma unroll
        for (int j = 0; j < 64; ++j) a = fmaf(r[j], r[j], a);
        ws[WS_CNORM + i] = a;
    }
}

// K1: one block (4 waves) per (n,h) row of 64 tokens; wave wi scans 128 codewords.
// wi forced to SGPR via readfirstlane so cb reads stay scalar (s_load).
__global__ __launch_bounds__(256, 4) void k_assign(const float* __restrict__ x,
                                                   const float* __restrict__ cb,
                                                   float* __restrict__ ws,
                                                   float* __restrict__ out) {
    const float* cnorm2 = ws + WS_CNORM;
    int* idx_out = (int*)(ws + WS_IDX);

    __shared__ float red_d[4][64];
    __shared__ int   red_i[4][64];

    const int row  = blockIdx.x;          // n*64 + h
    const int lane = threadIdx.x & 63;    // w
    const int wi   = threadIdx.x >> 6;    // wave 0..3 (divergent view, for LDS)
    // wave-uniform scalar copy: makes k-range (and cb addresses) provably uniform
    const int wi_s = __builtin_amdgcn_readfirstlane(wi);
    const int n = row >> 6, h = row & 63;
    const int base = n * CHW_ + h * Ww_ + lane;

    // full channel vector for this token (coalesced per channel)
    float xr[64];
#pragma unroll
    for (int c = 0; c < 64; ++c) xr[c] = x[base + c * HW_];

    float xn = 0.f;
#pragma unroll
    for (int c = 0; c < 64; ++c) xn = fmaf(xr[c], xr[c], xn);

    float best = __builtin_inff();
    const int k0 = wi_s * 128;            // SGPR -> uniform
    int bidx = k0;
    for (int k = k0; k < k0 + 128; ++k) {
        const float* __restrict__ cr = cb + k * 64;   // uniform -> s_load
        // 4 independent FMA chains to hide v_fmac dep latency
        float a0 = 0.f, a1 = 0.f, a2 = 0.f, a3 = 0.f;
#pragma unroll
        for (int j = 0; j < 64; j += 4) {
            a0 = fmaf(xr[j + 0], cr[j + 0], a0);
            a1 = fmaf(xr[j + 1], cr[j + 1], a1);
            a2 = fmaf(xr[j + 2], cr[j + 2], a2);
            a3 = fmaf(xr[j + 3], cr[j + 3], a3);
        }
        float acc = (a0 + a1) + (a2 + a3);
        float d2 = (xn - 2.0f * acc) + cnorm2[k];
        if (d2 < best) { best = d2; bidx = k; }       // strict < == first-min
    }

    red_d[wi][lane] = best;
    red_i[wi][lane] = bidx;
    __syncthreads();
    if (wi == 0) {
        float b = red_d[0][lane];
        int  bi = red_i[0][lane];
#pragma unroll
        for (int p = 1; p < 4; ++p) {
            float d = red_d[p][lane];
            if (d < b) { b = d; bi = red_i[p][lane]; }  // ascending ranges, strict <
        }
        red_i[0][lane] = bi;
        idx_out[row * 64 + lane] = bi;                  // coalesced
    }
    __syncthreads();
    const int fb = red_i[0][lane];
    const float* __restrict__ q = cb + fb * 64;         // L1/L2-hot gather
#pragma unroll
    for (int cc = 0; cc < 16; ++cc) {
        int c = wi * 16 + cc;
        out[base + c * HW_] = q[c];                     // coalesced store per channel
    }
}

// K2: block = (channel c, image s). Coalesced x/idx reads, LDS histogram scatter.
__global__ __launch_bounds__(256) void k_stats(const float* __restrict__ x,
                                               const float* __restrict__ ws_ro,
                                               float* __restrict__ ws) {
    const int* __restrict__ idx = (const int*)(ws_ro + WS_IDX);
    __shared__ float hist[512];
    __shared__ float hcnt[512];

    const int c = blockIdx.x & 63;
    const int s = blockIdx.x >> 6;
    const int tid = threadIdx.x;
    const bool docnt = (c == 0);

    hist[tid] = 0.f; hist[tid + 256] = 0.f;
    hcnt[tid] = 0.f; hcnt[tid + 256] = 0.f;
    __syncthreads();

    const float* __restrict__ xc = x + s * CHW_ + c * HW_;  // contiguous 16 KB
    const int tbase = s * HW_;
#pragma unroll 4
    for (int it = 0; it < 16; ++it) {
        int i = it * 256 + tid;
        int ii = idx[tbase + i];       // coalesced, L2-hot
        float xv = xc[i];              // coalesced
        atomicAdd(&hist[ii], xv);      // LDS scatter
        if (docnt) atomicAdd(&hcnt[ii], 1.0f);
    }
    __syncthreads();

    float* psum = ws + WS_PSUM + s * (K_ * Cc_) + c * K_;
    psum[tid] = hist[tid];
    psum[tid + 256] = hist[tid + 256];
    if (docnt) {
        float* pc = ws + WS_PCNT + s * K_;
        pc[tid] = hcnt[tid];
        pc[tid + 256] = hcnt[tid + 256];
    }
}

// K3: reduce slices, finalize EMA states and codebook_new
__global__ __launch_bounds__(256) void k_final(const float* __restrict__ Ns,
                                               const float* __restrict__ ms,
                                               const float* __restrict__ ws,
                                               float* __restrict__ out) {
    int j = blockIdx.x * 256 + threadIdx.x;  // j = c*512 + k  (coalesced partial reads)
    int c = j >> 9, k = j & 511;

    float s = 0.f, cnt = 0.f;
    for (int sl = 0; sl < S_; ++sl) {
        s   += ws[WS_PSUM + sl * (K_ * Cc_) + j];
        cnt += ws[WS_PCNT + sl * K_ + k];
    }

    const float gamma = 0.99f;
    const float omg   = (float)(1.0 - 0.99);

    bool occ = cnt > 0.0f;
    float Nv = Ns[k];
    float Nnew = occ ? (Nv * gamma + cnt * omg) : Nv;

    int i = k * 64 + c;
    float mv = ms[i];
    float mnew = occ ? (mv * gamma + s * omg) : mv;

    out[OFF_CB + i] = mnew / Nnew;
    out[OFF_M  + i] = mnew;
    if (c == 0) out[OFF_N + k] = Nnew;
}

extern "C" void kernel_launch(void* const* d_in, const int* in_sizes, int n_in,
                              void* d_out, int out_size, void* d_ws, size_t ws_size,
                              hipStream_t stream) {
    const float* x  = (const float*)d_in[0];
    const float* cb = (const float*)d_in[1];
    const float* Ns = (const float*)d_in[2];
    const float* ms = (const float*)d_in[3];
    float* out = (float*)d_out;
    float* ws  = (float*)d_ws;

    hipLaunchKernelGGL(k_prep,   dim3(2),           dim3(256), 0, stream, cb, ws);
    hipLaunchKernelGGL(k_assign, dim3(Nn_ * Hh_),   dim3(256), 0, stream, x, cb, ws, out);
    hipLaunchKernelGGL(k_stats,  dim3(S_ * Cc_),    dim3(256), 0, stream, x, ws, ws);
    hipLaunchKernelGGL(k_final,  dim3(32768 / 256), dim3(256), 0, stream, Ns, ms, ws, out);
}